// Round 4
// baseline (197.619 us; speedup 1.0000x reference)
//
#include <hip/hip_runtime.h>

#define NROW 8192
#define DIM  256
#define INV_T 5.0f
#define BM 128
#define BN 128
#define CSPLIT 8
#define COLS_PER_BLOCK (NROW / CSPLIT)   // 1024
#define NT 8                              // column tiles per block

typedef _Float16 f16x8 __attribute__((ext_vector_type(8)));
typedef _Float16 f16x4 __attribute__((ext_vector_type(4)));
typedef float    f32x4 __attribute__((ext_vector_type(4)));
typedef unsigned long long u64;

__device__ __forceinline__ void gload_lds16(const void* g, void* l) {
  __builtin_amdgcn_global_load_lds(
      (__attribute__((address_space(1))) void*)(g),
      (__attribute__((address_space(3))) void*)(l),
      16, 0, 0);
}

// ---------------- normalize rows + convert to fp16 ----------------
__global__ __launch_bounds__(256) void norm_kernel(
    const float* __restrict__ zv, const float* __restrict__ zf,
    _Float16* __restrict__ ov, _Float16* __restrict__ of) {
  const float* in  = blockIdx.y ? zf : zv;
  _Float16*    out = blockIdx.y ? of : ov;
  int row  = blockIdx.x * 4 + (threadIdx.x >> 6);
  int lane = threadIdx.x & 63;
  float4 v = ((const float4*)(in + (size_t)row * DIM))[lane];
  float ss = v.x * v.x + v.y * v.y + v.z * v.z + v.w * v.w;
#pragma unroll
  for (int off = 1; off < 64; off <<= 1) ss += __shfl_xor(ss, off);
  float inv = 1.0f / fmaxf(sqrtf(ss), 1e-12f);
  f16x4 o;
  o.x = (_Float16)(v.x * inv);
  o.y = (_Float16)(v.y * inv);
  o.z = (_Float16)(v.z * inv);
  o.w = (_Float16)(v.w * inv);
  ((f16x4*)(out + (size_t)row * DIM))[lane] = o;
}

// ---------------- fused GEMM + ballot-packed mask + exp/row-reductions ----------------
// Barrier-free main loop: A in LDS (read-only), B direct from L2, Gf pipelined
// through registers. Grid flat 512; by = bid%8 pins each column-split to one XCD.
__global__ __launch_bounds__(256, 2) void fused_kernel(
    const _Float16* __restrict__ zv, const _Float16* __restrict__ zf,
    const float* __restrict__ Gf,
    float* __restrict__ Sp, float* __restrict__ Pp, float* __restrict__ Cp) {

  __shared__ __align__(16) _Float16 Asf[BM * DIM];      // 64 KB, XOR-swizzled

  const int t_   = threadIdx.x;
  const int lane = t_ & 63;
  const int w    = t_ >> 6;
  const int wr   = w >> 1;
  const int wc   = w & 1;
  const int l15  = lane & 15;
  const int kq   = lane >> 4;
  const int bx   = blockIdx.x >> 3;
  const int by   = blockIdx.x & 7;       // = XCD id under round-robin dispatch
  const int row0 = bx * BM;
  const int col0 = by * COLS_PER_BLOCK;

  // ---- stage full A tile (128 x 256 fp16), source pre-swizzled ----
#pragma unroll
  for (int c = 0; c < 16; ++c) {
    int i = c * 256 + t_;
    int row = i >> 5, cbP = i & 31;
    int cbL = cbP ^ (row & 7);
    gload_lds16(zv + (size_t)(row0 + row) * DIM + cbL * 8,
                &Asf[(size_t)(c * 256 + w * 64) * 8]);
  }

  // Gf: wave (wr,wc) owns rows [wr*64,+64) x cols [wc*64,+64) of each tile.
  const float* gfbase = Gf + (size_t)(row0 + wr * 64 + kq) * NROW
                           + col0 + wc * 64 + l15 * 4;

  auto issueGf = [&](float4* q, int tt, int c0) {
    const float* p = gfbase + (size_t)tt * BN;
#pragma unroll
    for (int j = 0; j < 4; ++j)
      q[j] = *(const float4*)(p + (size_t)((c0 + j) * 4) * NROW);
  };

  // Ballot-pack 4 chunks into this lane's mask word; diagonal folded in.
  // Consumer bit for (m,n,r) is bit (r*16 + n*4) of wm[m].
  auto maskFrom4 = [&](const float4* q, int tt, int c0) -> u64 {
    int bd = (row0 + wr * 64 + kq) - (col0 + tt * BN + wc * 64 + l15 * 4);
    u64 e = 0;
#pragma unroll
    for (int j = 0; j < 4; ++j) {
      int d = bd + (c0 + j) * 4;
      u64 b0 = __ballot(q[j].x > 0.0f || d == 0);
      u64 b1 = __ballot(q[j].y > 0.0f || d == 1);
      u64 b2 = __ballot(q[j].z > 0.0f || d == 2);
      u64 b3 = __ballot(q[j].w > 0.0f || d == 3);
      u64 s01 = (l15 & 1) ? b1 : b0;
      u64 s23 = (l15 & 1) ? b3 : b2;
      u64 bsel = (l15 & 2) ? s23 : s01;
      u64 ej = bsel >> (l15 >> 2);
      e = (kq == j) ? ej : e;
    }
    return e;
  };

  // ---- prologue: masks for tile 0 (overlaps A staging; one-time sync) ----
  u64 wm[4];
  {
    float4 gp[8];
    issueGf(gp, 0, 0);  issueGf(gp + 4, 0, 4);
    wm[0] = maskFrom4(gp, 0, 0);
    wm[1] = maskFrom4(gp + 4, 0, 4);
    issueGf(gp, 0, 8);  issueGf(gp + 4, 0, 12);
    wm[2] = maskFrom4(gp, 0, 8);
    wm[3] = maskFrom4(gp + 4, 0, 12);
  }
  __syncthreads();   // A tile ready; last barrier in the kernel

  f32x4 acc[4][4];
  float Sa[16], Pa[16], Ca[16];
  u64 wn[4];
  float4 gvA[4], gvB[4];
#pragma unroll
  for (int i = 0; i < 16; ++i) { Sa[i] = 0.0f; Pa[i] = 0.0f; Ca[i] = 0.0f; }

#define STEP(KK)                                                               \
  do {                                                                         \
    if ((KK) == 0) {                                                           \
      _Pragma("unroll") for (int m = 0; m < 4; ++m)                            \
          _Pragma("unroll") for (int n = 0; n < 4; ++n)                        \
              acc[m][n] = (f32x4)(0.0f);                                       \
      if (t < NT - 1) issueGf(gvA, t + 1, 0);                                  \
    }                                                                          \
    if ((KK) == 1 && t < NT - 1) issueGf(gvB, t + 1, 4);                       \
    f16x8 af[4], bf[4];                                                        \
    bf[0] = *(const f16x8*)(bp0 + (KK) * 32 + kq * 8);                         \
    bf[1] = *(const f16x8*)(bp1 + (KK) * 32 + kq * 8);                         \
    bf[2] = *(const f16x8*)(bp2 + (KK) * 32 + kq * 8);                         \
    bf[3] = *(const f16x8*)(bp3 + (KK) * 32 + kq * 8);                         \
    _Pragma("unroll") for (int m = 0; m < 4; ++m) {                            \
      int row = wr * 64 + m * 16 + l15;                                        \
      int cbP = ((KK) * 4 + kq) ^ (row & 7);                                   \
      af[m] = *(const f16x8*)&Asf[(size_t)row * 256 + cbP * 8];                \
    }                                                                          \
    _Pragma("unroll") for (int m = 0; m < 4; ++m)                              \
        _Pragma("unroll") for (int n = 0; n < 4; ++n)                          \
            acc[m][n] = __builtin_amdgcn_mfma_f32_16x16x32_f16(                \
                af[m], bf[n], acc[m][n], 0, 0, 0);                             \
    if ((KK) == 3 && t < NT - 1) {                                             \
      wn[0] = maskFrom4(gvA, t + 1, 0);                                        \
      issueGf(gvA, t + 1, 8);                                                  \
    }                                                                          \
    if ((KK) == 4 && t < NT - 1) {                                             \
      wn[1] = maskFrom4(gvB, t + 1, 4);                                        \
      issueGf(gvB, t + 1, 12);                                                 \
    }                                                                          \
    if ((KK) == 6 && t < NT - 1) wn[2] = maskFrom4(gvA, t + 1, 8);             \
    if ((KK) == 7) {                                                           \
      if (t < NT - 1) wn[3] = maskFrom4(gvB, t + 1, 12);                       \
      _Pragma("unroll") for (int m = 0; m < 4; ++m) {                          \
        _Pragma("unroll") for (int n = 0; n < 4; ++n) {                        \
          _Pragma("unroll") for (int r = 0; r < 4; ++r) {                      \
            float sim = acc[m][n][r] * INV_T;                                  \
            bool pos = (((unsigned)(wm[m] >> (r * 16 + n * 4)) & 1u) != 0u);   \
            float e = __expf(sim);                                             \
            int idx = m * 4 + r;                                               \
            Sa[idx] += pos ? 1.0f : e;                                         \
            Pa[idx] += pos ? sim : 0.0f;                                       \
            Ca[idx] += pos ? 1.0f : 0.0f;                                      \
          }                                                                    \
        }                                                                      \
      }                                                                        \
      if (t < NT - 1) {                                                        \
        _Pragma("unroll") for (int i = 0; i < 4; ++i) wm[i] = wn[i];           \
      }                                                                        \
    }                                                                          \
  } while (0)

#pragma unroll 1
  for (int t = 0; t < NT; ++t) {
    const _Float16* brow = zf + (size_t)(col0 + t * BN + wc * 64 + l15) * DIM;
    const _Float16* bp0 = brow;
    const _Float16* bp1 = brow + 16 * DIM;
    const _Float16* bp2 = brow + 32 * DIM;
    const _Float16* bp3 = brow + 48 * DIM;
    STEP(0); STEP(1); STEP(2); STEP(3);
    STEP(4); STEP(5); STEP(6); STEP(7);
  }
#undef STEP

  // ---- reduce across the 16 column-lanes of each row group ----
#pragma unroll
  for (int off = 1; off <= 8; off <<= 1) {
#pragma unroll
    for (int i = 0; i < 16; ++i) {
      Sa[i] += __shfl_xor(Sa[i], off);
      Pa[i] += __shfl_xor(Pa[i], off);
      Ca[i] += __shfl_xor(Ca[i], off);
    }
  }
  const int slot = by * 2 + wc;
#pragma unroll
  for (int i = 0; i < 16; ++i) {
    if (l15 == i) {
      int m = i >> 2, r = i & 3;
      int row = row0 + wr * 64 + m * 16 + kq * 4 + r;
      Sp[(size_t)slot * NROW + row] = Sa[i];
      Pp[(size_t)slot * NROW + row] = Pa[i];
      Cp[(size_t)slot * NROW + row] = Ca[i];
    }
  }
}

// ---------------- per-row loss + block partials (deterministic) ----------------
__global__ __launch_bounds__(256) void loss_partial_kernel(
    const float* __restrict__ Sp, const float* __restrict__ Pp,
    const float* __restrict__ Cp, float* __restrict__ bsum) {
  int row = blockIdx.x * 256 + threadIdx.x;
  float S = 0.0f, P = 0.0f, C = 0.0f;
#pragma unroll
  for (int s2 = 0; s2 < 16; ++s2) {
    S += Sp[(size_t)s2 * NROW + row];
    P += Pp[(size_t)s2 * NROW + row];
    C += Cp[(size_t)s2 * NROW + row];
  }
  float pos = P / (C + 1e-8f);
  float contrib = __logf(S + __expf(pos)) - pos;
#pragma unroll
  for (int off = 1; off < 64; off <<= 1) contrib += __shfl_xor(contrib, off);
  __shared__ float wsum[4];
  if ((threadIdx.x & 63) == 0) wsum[threadIdx.x >> 6] = contrib;
  __syncthreads();
  if (threadIdx.x == 0) bsum[blockIdx.x] = wsum[0] + wsum[1] + wsum[2] + wsum[3];
}

__global__ void loss_final_kernel(const float* __restrict__ bsum, float* __restrict__ out) {
  int lane = threadIdx.x;
  float v = (lane < 32) ? bsum[lane] : 0.0f;
#pragma unroll
  for (int off = 1; off < 64; off <<= 1) v += __shfl_xor(v, off);
  if (lane == 0) out[0] = v / (float)NROW;
}

extern "C" void kernel_launch(void* const* d_in, const int* in_sizes, int n_in,
                              void* d_out, int out_size, void* d_ws, size_t ws_size,
                              hipStream_t stream) {
  const float* zv = (const float*)d_in[0];
  const float* zf = (const float*)d_in[1];
  const float* Gf = (const float*)d_in[2];
  float* out = (float*)d_out;

  char* ws = (char*)d_ws;
  _Float16* zv16 = (_Float16*)ws;
  _Float16* zf16 = zv16 + (size_t)NROW * DIM;
  float* Sp = (float*)(ws + 2 * (size_t)NROW * DIM * sizeof(_Float16));
  float* Pp = Sp + 16 * (size_t)NROW;
  float* Cp = Pp + 16 * (size_t)NROW;
  float* bsum = Cp + 16 * (size_t)NROW;

  norm_kernel<<<dim3(NROW / 4, 2), 256, 0, stream>>>(zv, zf, zv16, zf16);
  fused_kernel<<<512, 256, 0, stream>>>(zv16, zf16, Gf, Sp, Pp, Cp);
  loss_partial_kernel<<<NROW / 256, 256, 0, stream>>>(Sp, Pp, Cp, bsum);
  loss_final_kernel<<<1, 64, 0, stream>>>(bsum, out);
}